// Round 7
// baseline (77.304 us; speedup 1.0000x reference)
//
#include <hip/hip_runtime.h>
#include <math.h>

#define NLEV   16
#define TSIZE  524288
#define TMASK  524287
#define NPIX   (1024*1024)

typedef __attribute__((ext_vector_type(8))) short s8v;
typedef __attribute__((ext_vector_type(4))) float f4v;

struct ResArr { float r[NLEV]; };
union Frag { unsigned int u[4]; s8v v; };

__device__ __forceinline__ unsigned short bf16_rn(float x) {
    unsigned int u = __builtin_bit_cast(unsigned int, x);
    u += 0x7fffu + ((u >> 16) & 1u);
    return (unsigned short)(u >> 16);
}
// truncating bf16 pack: one v_perm_b32 (values ~1e-4 vs 1e-2 threshold).
__device__ __forceinline__ unsigned int pk_bf16(float lo, float hi) {
    return __builtin_amdgcn_perm(__builtin_bit_cast(unsigned int, hi),
                                 __builtin_bit_cast(unsigned int, lo),
                                 0x07060302u);
}

// ws layout (float offsets): [0..15] res f32; [16..271] W3 padded [64][4] f32;
// at float offset 272: W1^T bf16 [64][32], then W2^T-permuted bf16 [64][64].
// W2's contraction dim is stored PERMUTED: physical k bits [st|g1 g0|j2 j1 j0]
// hold logical k bits [st|j2|g1 g0|j1 j0], so that layer-2 B-fragments are
// exactly the lane-local layer-1 output words (no LDS/shuffle exchange).
__global__ __launch_bounds__(256) void prep_kernel(
    const float* __restrict__ W1, const float* __restrict__ W2,
    const float* __restrict__ W3, float* __restrict__ ws, ResArr res)
{
    const int t = threadIdx.x;
    if (t < NLEV) ws[t] = res.r[t];
    float* w3p = ws + 16;
    unsigned short* w1t = (unsigned short*)(ws + 272);
    unsigned short* w2t = w1t + 64 * 32;
    for (int i = t; i < 64 * 4; i += 256) {
        int r = i >> 2, c = i & 3;
        w3p[i] = (c < 3) ? W3[r * 3 + c] : 0.0f;
    }
    for (int i = t; i < 64 * 32; i += 256) {
        int n = i >> 5, k = i & 31;
        w1t[i] = bf16_rn(W1[k * 64 + n]);
    }
    for (int i = t; i < 64 * 64; i += 256) {
        int n2 = i >> 6, kp = i & 63;
        int klog = (kp & 32) | ((kp & 4) << 2) | ((kp & 24) >> 1) | (kp & 3);
        w2t[i] = bf16_rn(W2[klog * 64 + n2]);
    }
}

// Block = 4 independent waves; wave wv covers rows yb+wv*4..+3, cols xb..xb+15.
// Lane (c15 = l&15, g = l>>4). GEMM pixel px = pt*16 + c15 = (x = xb+c15,
// y = yb+wv*4+pt). MLP in swapped form D' = W^T * act^T; h1 stays entirely in
// registers via the W2 contraction-permutation (see prep). No LDS.
// amdgpu_waves_per_eu(4,4): rounds 4-6 showed the scheduler targets 7-8
// waves/SIMD on its own and clamps VGPR to 64-68, serializing the gather
// batches. Pinning min=max=4 frees the allocator to use up to 128 VGPRs for
// the 2-deep software-pipelined encode below.
__global__ __launch_bounds__(256) __attribute__((amdgpu_waves_per_eu(4, 4)))
void ngp_mfma_kernel(
    const float* __restrict__ tables,
    const float* __restrict__ b1, const float* __restrict__ b2,
    const float* __restrict__ b3,
    const float* __restrict__ ws, float* __restrict__ out)
{
    const int tid  = threadIdx.x;
    const int lane = tid & 63;
    const int wv   = tid >> 6;
    const int c15  = lane & 15;
    const int g    = lane >> 4;
    const int xb   = blockIdx.x * 16;
    const int yb   = blockIdx.y * 16;

    const float4 rv = *(const float4*)(ws + g * 4);
    const float rr[4] = { rv.x, rv.y, rv.z, rv.w };
    const float xs = (float)(xb + c15) * (1.0f / 1024.0f);
    float yf[4];
    #pragma unroll
    for (int pt = 0; pt < 4; ++pt)
        yf[pt] = (float)(yb + wv * 4 + pt) * (1.0f / 1024.0f);

    const float2* __restrict__ tabg = (const float2*)tables + (size_t)(g * 4) * TSIZE;

    // ---- encode: 2-deep software pipeline over level batches.
    //      ISSUE(J,B): compute hashes, launch 16 gathers into fb[B]; the asm
    //      memory-clobber pins the loads before any later arithmetic.
    //      CONSUME(J,B): bilerp fb[B] -> bfrag[.].u[J]. ----
    float2 fb[2][4][4];
    float  fxb[2];
    float  fyb[2][4];
    Frag   bfrag[4];

#define NGP_ISSUE(J, B) do {                                                  \
    const float r_   = rr[J];                                                 \
    const float sx_  = xs * r_;                                               \
    const float fx0_ = floorf(sx_);                                           \
    fxb[B] = sx_ - fx0_;                                                      \
    const unsigned int cx_  = (unsigned int)fx0_;                             \
    const unsigned int cx1_ = cx_ + 1u;                                       \
    const float2* __restrict__ tab_ = tabg + (size_t)(J) * TSIZE;             \
    _Pragma("unroll")                                                         \
    for (int pt_ = 0; pt_ < 4; ++pt_) {                                       \
        const float sy_  = yf[pt_] * r_;                                      \
        const float fy0_ = floorf(sy_);                                       \
        fyb[B][pt_] = sy_ - fy0_;                                             \
        const unsigned int cy_  = (unsigned int)fy0_;                         \
        const unsigned int hy0_ = cy_ * 2654435761u;                          \
        const unsigned int hy1_ = hy0_ + 2654435761u;                         \
        fb[B][pt_][0] = tab_[(cx_  ^ hy0_) & TMASK];                          \
        fb[B][pt_][1] = tab_[(cx1_ ^ hy0_) & TMASK];                          \
        fb[B][pt_][2] = tab_[(cx_  ^ hy1_) & TMASK];                          \
        fb[B][pt_][3] = tab_[(cx1_ ^ hy1_) & TMASK];                          \
    }                                                                         \
    asm volatile("" ::: "memory");                                            \
} while (0)

#define NGP_CONSUME(J, B) do {                                                \
    const float fx_ = fxb[B];                                                 \
    _Pragma("unroll")                                                         \
    for (int pt_ = 0; pt_ < 4; ++pt_) {                                       \
        const float fy_  = fyb[B][pt_];                                       \
        const float w00_ = (1.0f - fx_) * (1.0f - fy_);                       \
        const float w10_ = fx_          * (1.0f - fy_);                       \
        const float w01_ = (1.0f - fx_) * fy_;                                \
        const float w11_ = fx_          * fy_;                                \
        const float e0_ = w00_ * fb[B][pt_][0].x + w10_ * fb[B][pt_][1].x     \
                        + w01_ * fb[B][pt_][2].x + w11_ * fb[B][pt_][3].x;    \
        const float e1_ = w00_ * fb[B][pt_][0].y + w10_ * fb[B][pt_][1].y     \
                        + w01_ * fb[B][pt_][2].y + w11_ * fb[B][pt_][3].y;    \
        bfrag[pt_].u[J] = pk_bf16(e0_, e1_);                                  \
    }                                                                         \
} while (0)

    const unsigned short* __restrict__ w1t = (const unsigned short*)(ws + 272);
    const unsigned short* __restrict__ w2t = w1t + 64 * 32;
    Frag afr[4];

    NGP_ISSUE(0, 0);
    NGP_ISSUE(1, 1);
    NGP_CONSUME(0, 0);
    NGP_ISSUE(2, 0);
    NGP_CONSUME(1, 1);
    NGP_ISSUE(3, 1);
    // prefetch layer-1 A-fragments under the tail of the encode
    #pragma unroll
    for (int mt = 0; mt < 4; ++mt)
        afr[mt].v = *(const s8v*)(w1t + (mt * 16 + c15) * 32 + g * 8);
    asm volatile("" ::: "memory");
    NGP_CONSUME(2, 0);
    NGP_CONSUME(3, 1);

#undef NGP_ISSUE
#undef NGP_CONSUME

    // ---- layer 1: D1'[n][px] = W1^T(64x32) * enc^T(32x64); bias+relu+pack
    //      into lane-local hp words (h1[n = mt*16+g*4+{r}] of px = pt*16+c15) ----
    unsigned int hp[4][4][2];
    #pragma unroll
    for (int mt = 0; mt < 4; ++mt) {
        const float4 bb = *(const float4*)(b1 + mt * 16 + g * 4);
        #pragma unroll
        for (int pt = 0; pt < 4; ++pt) {
            f4v acc = (f4v){0.f, 0.f, 0.f, 0.f};
            acc = __builtin_amdgcn_mfma_f32_16x16x32_bf16(
                afr[mt].v, bfrag[pt].v, acc, 0, 0, 0);
            const float v0 = fmaxf(acc[0] + bb.x, 0.0f);
            const float v1 = fmaxf(acc[1] + bb.y, 0.0f);
            const float v2 = fmaxf(acc[2] + bb.z, 0.0f);
            const float v3 = fmaxf(acc[3] + bb.w, 0.0f);
            hp[mt][pt][0] = pk_bf16(v0, v1);
            hp[mt][pt][1] = pk_bf16(v2, v3);
        }
    }

    // ---- layer 2: B-frags are the lane's own hp words (k-permuted W2) ----
    f4v acc2[4][4];
    #pragma unroll
    for (int mt = 0; mt < 4; ++mt)
        #pragma unroll
        for (int pt = 0; pt < 4; ++pt)
            acc2[mt][pt] = (f4v){0.f, 0.f, 0.f, 0.f};
    #pragma unroll
    for (int st = 0; st < 2; ++st) {
        Frag a2[4], bf2[4];
        #pragma unroll
        for (int mt = 0; mt < 4; ++mt)
            a2[mt].v = *(const s8v*)(w2t + (mt * 16 + c15) * 64 + st * 32 + g * 8);
        #pragma unroll
        for (int pt = 0; pt < 4; ++pt) {
            bf2[pt].u[0] = hp[2 * st + 0][pt][0];
            bf2[pt].u[1] = hp[2 * st + 0][pt][1];
            bf2[pt].u[2] = hp[2 * st + 1][pt][0];
            bf2[pt].u[3] = hp[2 * st + 1][pt][1];
        }
        #pragma unroll
        for (int mt = 0; mt < 4; ++mt)
            #pragma unroll
            for (int pt = 0; pt < 4; ++pt)
                acc2[mt][pt] = __builtin_amdgcn_mfma_f32_16x16x32_bf16(
                    a2[mt].v, bf2[pt].v, acc2[mt][pt], 0, 0, 0);
    }

    // ---- bias + relu, layer 3 (64 -> 3) on VALU, butterfly over g ----
    const float* __restrict__ w3p = ws + 16;
    float part[4][3] = {{0,0,0},{0,0,0},{0,0,0},{0,0,0}};
    #pragma unroll
    for (int mt = 0; mt < 4; ++mt) {
        const float4 bb2 = *(const float4*)(b2 + mt * 16 + g * 4);
        const float bbv[4] = { bb2.x, bb2.y, bb2.z, bb2.w };
        #pragma unroll
        for (int r = 0; r < 4; ++r) {
            const float4 w3 = *(const float4*)(w3p + (size_t)(mt * 16 + g * 4 + r) * 4);
            #pragma unroll
            for (int pt = 0; pt < 4; ++pt) {
                const float h = fmaxf(acc2[mt][pt][r] + bbv[r], 0.0f);
                part[pt][0] = fmaf(h, w3.x, part[pt][0]);
                part[pt][1] = fmaf(h, w3.y, part[pt][1]);
                part[pt][2] = fmaf(h, w3.z, part[pt][2]);
            }
        }
    }
    #pragma unroll
    for (int pt = 0; pt < 4; ++pt)
        #pragma unroll
        for (int c = 0; c < 3; ++c) {
            float v = part[pt][c];
            v += __shfl_xor(v, 16);
            v += __shfl_xor(v, 32);
            part[pt][c] = v;
        }
    float o0 = 0.f, o1 = 0.f, o2 = 0.f;
    #pragma unroll
    for (int pt = 0; pt < 4; ++pt) {
        if (g == pt) { o0 = part[pt][0]; o1 = part[pt][1]; o2 = part[pt][2]; }
    }
    o0 += b3[0]; o1 += b3[1]; o2 += b3[2];
    const int pix = ((yb + wv * 4 + g) << 10) + xb + c15;
    out[0 * NPIX + pix] = 1.0f / (1.0f + __expf(-o0));
    out[1 * NPIX + pix] = 1.0f / (1.0f + __expf(-o1));
    out[2 * NPIX + pix] = 1.0f / (1.0f + __expf(-o2));
}

extern "C" void kernel_launch(void* const* d_in, const int* in_sizes, int n_in,
                              void* d_out, int out_size, void* d_ws, size_t ws_size,
                              hipStream_t stream) {
    const float* tables = (const float*)d_in[0];
    const float* W1     = (const float*)d_in[1];
    const float* b1     = (const float*)d_in[2];
    const float* W2     = (const float*)d_in[3];
    const float* b2     = (const float*)d_in[4];
    const float* W3     = (const float*)d_in[5];
    const float* b3     = (const float*)d_in[6];
    float* out          = (float*)d_out;
    float* ws           = (float*)d_ws;

    ResArr res;
    const double growth = exp((log(1024.0) - log(16.0)) / 15.0);
    for (int l = 0; l < NLEV; ++l)
        res.r[l] = (float)floor(16.0 * pow(growth, (double)l));

    hipLaunchKernelGGL(prep_kernel, dim3(1), dim3(256), 0, stream, W1, W2, W3, ws, res);
    hipLaunchKernelGGL(ngp_mfma_kernel, dim3(64, 64), dim3(256), 0, stream,
                       tables, b1, b2, b3, ws, out);
}

// Round 8
// 67.929 us; speedup vs baseline: 1.1380x; 1.1380x over previous
//
#include <hip/hip_runtime.h>
#include <math.h>

#define NLEV   16
#define TSIZE  524288
#define TMASK  524287
#define NPIX   (1024*1024)

typedef __attribute__((ext_vector_type(8))) short s8v;
typedef __attribute__((ext_vector_type(4))) float f4v;

struct ResArr { float r[NLEV]; };
union Frag { unsigned int u[4]; s8v v; };

__device__ __forceinline__ unsigned short bf16_rn(float x) {
    unsigned int u = __builtin_bit_cast(unsigned int, x);
    u += 0x7fffu + ((u >> 16) & 1u);
    return (unsigned short)(u >> 16);
}
// truncating bf16 pack: one v_perm_b32 (values ~1e-4 vs 1e-2 threshold).
__device__ __forceinline__ unsigned int pk_bf16(float lo, float hi) {
    return __builtin_amdgcn_perm(__builtin_bit_cast(unsigned int, hi),
                                 __builtin_bit_cast(unsigned int, lo),
                                 0x07060302u);
}

// ws layout: [0..15] res f32. Then ushort region at ws+16:
//   w1t: W1^T bf16 [64][32]          (2048 ushort)
//   w2t: W2^T k-permuted bf16 [64][64] (4096 ushort)
//   w3t: W3^T k-permuted, row-replicated bf16 [16][64] (1024 ushort)
// k-permutation (w2t, w3t): physical k bits [st|g1 g0|j2 j1 j0] hold logical
// [st|j2|g1 g0|j1 j0] so the next layer's B-fragments are exactly the lane's
// own previous-layer output words (no LDS/shuffle exchange).
// w3t row r holds output channel r%4 (zeros for r%4==3): every lane's layer-3
// accumulator reg r = channel r, regardless of lane group g.
__global__ __launch_bounds__(256) void prep_kernel(
    const float* __restrict__ W1, const float* __restrict__ W2,
    const float* __restrict__ W3, float* __restrict__ ws, ResArr res)
{
    const int t = threadIdx.x;
    if (t < NLEV) ws[t] = res.r[t];
    unsigned short* w1t = (unsigned short*)(ws + 16);
    unsigned short* w2t = w1t + 64 * 32;
    unsigned short* w3t = w2t + 64 * 64;
    for (int i = t; i < 64 * 32; i += 256) {
        int n = i >> 5, k = i & 31;
        w1t[i] = bf16_rn(W1[k * 64 + n]);
    }
    for (int i = t; i < 64 * 64; i += 256) {
        int n2 = i >> 6, kp = i & 63;
        int klog = (kp & 32) | ((kp & 4) << 2) | ((kp & 24) >> 1) | (kp & 3);
        w2t[i] = bf16_rn(W2[klog * 64 + n2]);
    }
    for (int i = t; i < 16 * 64; i += 256) {
        int row = i >> 6, kp = i & 63;
        int klog = (kp & 32) | ((kp & 4) << 2) | ((kp & 24) >> 1) | (kp & 3);
        int ch = row & 3;
        w3t[i] = (ch < 3) ? bf16_rn(W3[klog * 3 + ch]) : (unsigned short)0;
    }
}

// Block = 4 independent waves; wave wv covers rows yb+wv*4..+3, cols xb..xb+15.
// Lane (c15 = l&15, g = l>>4). GEMM pixel px = pt*16 + c15 = (x = xb+c15,
// y = yb+wv*4+pt). All three MLP layers on MFMA in swapped form D' = W^T*act^T;
// activations never leave registers (k-permuted weights, see prep). No LDS.
// Layer-2/3 accumulators are phase-split (16 AGPRs live at a time, not 64):
// rounds 5-7 showed the 64-AGPR acc2 footprint was starving the arch-VGPR
// side and spilling the gather pipeline to scratch.
__global__ __launch_bounds__(256) void ngp_mfma_kernel(
    const float* __restrict__ tables,
    const float* __restrict__ b1, const float* __restrict__ b2,
    const float* __restrict__ b3,
    const float* __restrict__ ws, float* __restrict__ out)
{
    const int tid  = threadIdx.x;
    const int lane = tid & 63;
    const int wv   = tid >> 6;
    const int c15  = lane & 15;
    const int g    = lane >> 4;
    const int xb   = blockIdx.x * 16;
    const int yb   = blockIdx.y * 16;

    const float4 rv = *(const float4*)(ws + g * 4);
    const float rr[4] = { rv.x, rv.y, rv.z, rv.w };
    const float xs = (float)(xb + c15) * (1.0f / 1024.0f);
    float yf[4];
    #pragma unroll
    for (int pt = 0; pt < 4; ++pt)
        yf[pt] = (float)(yb + wv * 4 + pt) * (1.0f / 1024.0f);

    const float2* __restrict__ tabg = (const float2*)tables + (size_t)(g * 4) * TSIZE;

    // ---- encode: 2-deep software pipeline over level batches ----
    float2 fb[2][4][4];
    float  fxb[2];
    float  fyb[2][4];
    Frag   bfrag[4];

#define NGP_ISSUE(J, B) do {                                                  \
    const float r_   = rr[J];                                                 \
    const float sx_  = xs * r_;                                               \
    const float fx0_ = floorf(sx_);                                           \
    fxb[B] = sx_ - fx0_;                                                      \
    const unsigned int cx_  = (unsigned int)fx0_;                             \
    const unsigned int cx1_ = cx_ + 1u;                                       \
    const float2* __restrict__ tab_ = tabg + (size_t)(J) * TSIZE;             \
    _Pragma("unroll")                                                         \
    for (int pt_ = 0; pt_ < 4; ++pt_) {                                       \
        const float sy_  = yf[pt_] * r_;                                      \
        const float fy0_ = floorf(sy_);                                       \
        fyb[B][pt_] = sy_ - fy0_;                                             \
        const unsigned int cy_  = (unsigned int)fy0_;                         \
        const unsigned int hy0_ = cy_ * 2654435761u;                          \
        const unsigned int hy1_ = hy0_ + 2654435761u;                         \
        fb[B][pt_][0] = tab_[(cx_  ^ hy0_) & TMASK];                          \
        fb[B][pt_][1] = tab_[(cx1_ ^ hy0_) & TMASK];                          \
        fb[B][pt_][2] = tab_[(cx_  ^ hy1_) & TMASK];                          \
        fb[B][pt_][3] = tab_[(cx1_ ^ hy1_) & TMASK];                          \
    }                                                                         \
    asm volatile("" ::: "memory");                                            \
} while (0)

#define NGP_CONSUME(J, B) do {                                                \
    const float fx_ = fxb[B];                                                 \
    _Pragma("unroll")                                                         \
    for (int pt_ = 0; pt_ < 4; ++pt_) {                                       \
        const float fy_  = fyb[B][pt_];                                       \
        const float w00_ = (1.0f - fx_) * (1.0f - fy_);                       \
        const float w10_ = fx_          * (1.0f - fy_);                       \
        const float w01_ = (1.0f - fx_) * fy_;                                \
        const float w11_ = fx_          * fy_;                                \
        const float e0_ = w00_ * fb[B][pt_][0].x + w10_ * fb[B][pt_][1].x     \
                        + w01_ * fb[B][pt_][2].x + w11_ * fb[B][pt_][3].x;    \
        const float e1_ = w00_ * fb[B][pt_][0].y + w10_ * fb[B][pt_][1].y     \
                        + w01_ * fb[B][pt_][2].y + w11_ * fb[B][pt_][3].y;    \
        bfrag[pt_].u[J] = pk_bf16(e0_, e1_);                                  \
    }                                                                         \
} while (0)

    const unsigned short* __restrict__ w1t = (const unsigned short*)(ws + 16);
    const unsigned short* __restrict__ w2t = w1t + 64 * 32;
    const unsigned short* __restrict__ w3t = w2t + 64 * 64;
    Frag afr[4];

    NGP_ISSUE(0, 0);
    NGP_ISSUE(1, 1);
    NGP_CONSUME(0, 0);
    NGP_ISSUE(2, 0);
    NGP_CONSUME(1, 1);
    NGP_ISSUE(3, 1);
    // prefetch layer-1 A-fragments under the tail of the encode
    #pragma unroll
    for (int mt = 0; mt < 4; ++mt)
        afr[mt].v = *(const s8v*)(w1t + (mt * 16 + c15) * 32 + g * 8);
    asm volatile("" ::: "memory");
    NGP_CONSUME(2, 0);
    NGP_CONSUME(3, 1);

#undef NGP_ISSUE
#undef NGP_CONSUME

    // ---- layer 1: bias+relu+pack into lane-local hp words
    //      (h1[n = mt*16+g*4+{r}] of px = pt*16+c15) ----
    unsigned int hp[4][4][2];
    #pragma unroll
    for (int mt = 0; mt < 4; ++mt) {
        const float4 bb = *(const float4*)(b1 + mt * 16 + g * 4);
        #pragma unroll
        for (int pt = 0; pt < 4; ++pt) {
            f4v acc = (f4v){0.f, 0.f, 0.f, 0.f};
            acc = __builtin_amdgcn_mfma_f32_16x16x32_bf16(
                afr[mt].v, bfrag[pt].v, acc, 0, 0, 0);
            const float v0 = fmaxf(acc[0] + bb.x, 0.0f);
            const float v1 = fmaxf(acc[1] + bb.y, 0.0f);
            const float v2 = fmaxf(acc[2] + bb.z, 0.0f);
            const float v3 = fmaxf(acc[3] + bb.w, 0.0f);
            hp[mt][pt][0] = pk_bf16(v0, v1);
            hp[mt][pt][1] = pk_bf16(v2, v3);
        }
    }

    // ---- layer 2: per-mt accumulator split (peak 16 AGPRs, not 64);
    //      B-frags are the lane's own hp words (k-permuted W2) ----
    unsigned int hq[4][4][2];
    #pragma unroll
    for (int mt = 0; mt < 4; ++mt) {
        const float4 bb2 = *(const float4*)(b2 + mt * 16 + g * 4);
        f4v acc[4];
        #pragma unroll
        for (int pt = 0; pt < 4; ++pt) acc[pt] = (f4v){0.f, 0.f, 0.f, 0.f};
        #pragma unroll
        for (int st = 0; st < 2; ++st) {
            Frag a2, bf2[4];
            a2.v = *(const s8v*)(w2t + (mt * 16 + c15) * 64 + st * 32 + g * 8);
            #pragma unroll
            for (int pt = 0; pt < 4; ++pt) {
                bf2[pt].u[0] = hp[2 * st + 0][pt][0];
                bf2[pt].u[1] = hp[2 * st + 0][pt][1];
                bf2[pt].u[2] = hp[2 * st + 1][pt][0];
                bf2[pt].u[3] = hp[2 * st + 1][pt][1];
            }
            #pragma unroll
            for (int pt = 0; pt < 4; ++pt)
                acc[pt] = __builtin_amdgcn_mfma_f32_16x16x32_bf16(
                    a2.v, bf2[pt].v, acc[pt], 0, 0, 0);
        }
        #pragma unroll
        for (int pt = 0; pt < 4; ++pt) {
            const float v0 = fmaxf(acc[pt][0] + bb2.x, 0.0f);
            const float v1 = fmaxf(acc[pt][1] + bb2.y, 0.0f);
            const float v2 = fmaxf(acc[pt][2] + bb2.z, 0.0f);
            const float v3 = fmaxf(acc[pt][3] + bb2.w, 0.0f);
            hq[mt][pt][0] = pk_bf16(v0, v1);
            hq[mt][pt][1] = pk_bf16(v2, v3);
        }
    }

    // ---- layer 3 on MFMA: W3^T row-replicated so acc3[pt] reg r = channel r
    //      of pixel (pt,c15) on every lane; lane keeps pt == g ----
    f4v acc3[4];
    #pragma unroll
    for (int pt = 0; pt < 4; ++pt) acc3[pt] = (f4v){0.f, 0.f, 0.f, 0.f};
    #pragma unroll
    for (int st = 0; st < 2; ++st) {
        Frag a3, bf3[4];
        a3.v = *(const s8v*)(w3t + c15 * 64 + st * 32 + g * 8);
        #pragma unroll
        for (int pt = 0; pt < 4; ++pt) {
            bf3[pt].u[0] = hq[2 * st + 0][pt][0];
            bf3[pt].u[1] = hq[2 * st + 0][pt][1];
            bf3[pt].u[2] = hq[2 * st + 1][pt][0];
            bf3[pt].u[3] = hq[2 * st + 1][pt][1];
        }
        #pragma unroll
        for (int pt = 0; pt < 4; ++pt)
            acc3[pt] = __builtin_amdgcn_mfma_f32_16x16x32_bf16(
                a3.v, bf3[pt].v, acc3[pt], 0, 0, 0);
    }

    float ov[3];
    #pragma unroll
    for (int c = 0; c < 3; ++c) {
        float v = acc3[0][c];
        v = (g == 1) ? acc3[1][c] : v;
        v = (g == 2) ? acc3[2][c] : v;
        v = (g == 3) ? acc3[3][c] : v;
        ov[c] = v + b3[c];
    }
    const int pix = ((yb + wv * 4 + g) << 10) + xb + c15;
    out[0 * NPIX + pix] = 1.0f / (1.0f + __expf(-ov[0]));
    out[1 * NPIX + pix] = 1.0f / (1.0f + __expf(-ov[1]));
    out[2 * NPIX + pix] = 1.0f / (1.0f + __expf(-ov[2]));
}

extern "C" void kernel_launch(void* const* d_in, const int* in_sizes, int n_in,
                              void* d_out, int out_size, void* d_ws, size_t ws_size,
                              hipStream_t stream) {
    const float* tables = (const float*)d_in[0];
    const float* W1     = (const float*)d_in[1];
    const float* b1     = (const float*)d_in[2];
    const float* W2     = (const float*)d_in[3];
    const float* b2     = (const float*)d_in[4];
    const float* W3     = (const float*)d_in[5];
    const float* b3     = (const float*)d_in[6];
    float* out          = (float*)d_out;
    float* ws           = (float*)d_ws;

    ResArr res;
    const double growth = exp((log(1024.0) - log(16.0)) / 15.0);
    for (int l = 0; l < NLEV; ++l)
        res.r[l] = (float)floor(16.0 * pow(growth, (double)l));

    hipLaunchKernelGGL(prep_kernel, dim3(1), dim3(256), 0, stream, W1, W2, W3, ws, res);
    hipLaunchKernelGGL(ngp_mfma_kernel, dim3(64, 64), dim3(256), 0, stream,
                       tables, b1, b2, b3, ws, out);
}